// Round 3
// baseline (1549.609 us; speedup 1.0000x reference)
//
#include <hip/hip_runtime.h>
#include <hip/hip_bf16.h>
#include <stdint.h>

typedef __hip_bfloat16 bf16;
typedef __attribute__((ext_vector_type(8))) __bf16 bf16x8;
typedef __attribute__((ext_vector_type(4))) float f32x4;

#define GN_EPS 1e-5f

__device__ __forceinline__ float silu_f(float x) {
  return x / (1.f + __expf(-x));
}

// dtype-dual scalar load: flag==1 -> f32 data, flag==0 -> bf16 data
__device__ __forceinline__ float ldf(const void* p, size_t i, int f) {
  return f ? ((const float*)p)[i]
           : __bfloat162float(((const bf16*)p)[i]);
}

// ---------------- dtype detect: scan gn1_w as bf16 halves -------------------
// If the tensor is really f32 (~1.0 each), its low mantissa halves decode as
// huge bf16 values (>1e4) with overwhelming probability. If really bf16, all
// values are |v| <= ~2.
__global__ void detect_k(const void* __restrict__ gn1w, int* __restrict__ flag) {
  if (threadIdx.x == 0 && blockIdx.x == 0) {
    const unsigned short* u = (const unsigned short*)gn1w;
    float mx = 0.f;
    for (int i = 0; i < 128; ++i) {
      unsigned int b = ((unsigned int)u[i]) << 16;
      float v = __uint_as_float(b);
      v = fabsf(v);
      if (!isnan(v) && v > mx) mx = v;
    }
    flag[0] = (mx > 1e4f) ? 1 : 0;
  }
}

// ---------------- transpose (K, CI, CO) -> (K, CO, CI), out bf16 ------------
__global__ void transpose_k(const void* __restrict__ in, bf16* __restrict__ out,
                            int CI, int CO, const int* __restrict__ flagp) {
  const int f = *flagp;
  int k = blockIdx.y;
  int ntco = CO >> 5;
  int tci = blockIdx.x / ntco, tco = blockIdx.x % ntco;
  __shared__ float t[32][33];
  int tx = threadIdx.x & 31, ty = threadIdx.x >> 5;
  size_t base = (size_t)k * CI * CO;
  bf16* dst = out + base;
#pragma unroll
  for (int j = 0; j < 4; ++j)
    t[ty + 8 * j][tx] =
        ldf(in, base + (size_t)(tci * 32 + ty + 8 * j) * CO + tco * 32 + tx, f);
  __syncthreads();
#pragma unroll
  for (int j = 0; j < 4; ++j)
    dst[(size_t)(tco * 32 + ty + 8 * j) * CI + tci * 32 + tx] =
        __float2bfloat16(t[tx][ty + 8 * j]);
}

// ---------------- group-norm stats: sum/sumsq per group ----
__global__ void gn_stats_k(const void* __restrict__ x, float* __restrict__ raw,
                           int rows, int C, const int* __restrict__ flagp) {
  const int f = *flagp;
  int tid = threadIdx.x;
  int rpb = 256 / C;            // rows per block-iteration (2 for C=128, 1 for C=256)
  int c = tid & (C - 1);
  int stripe = tid / C;
  float s = 0.f, sq = 0.f;
  for (int r = blockIdx.x * rpb + stripe; r < rows; r += gridDim.x * rpb) {
    float v = ldf(x, (size_t)r * C + c, f);
    s += v; sq += v * v;
  }
  __shared__ float ls[256], lq[256];
  ls[tid] = s; lq[tid] = sq;
  __syncthreads();
  if (tid < 32) {
    int per = C >> 5;           // channels per group
    float as = 0.f, aq = 0.f;
    for (int st = 0; st < rpb; ++st)
      for (int e = 0; e < per; ++e) {
        int idx = st * C + tid * per + e;
        as += ls[idx]; aq += lq[idx];
      }
    atomicAdd(&raw[tid], as);
    atomicAdd(&raw[32 + tid], aq);
  }
}

__global__ void gn_fin_k(const float* __restrict__ raw, float* __restrict__ fin,
                         float count) {
  int g = threadIdx.x;
  if (g < 32) {
    float mu = raw[g] / count;
    float var = fmaxf(raw[32 + g] / count - mu * mu, 0.f);
    fin[g] = mu;
    fin[32 + g] = rsqrtf(var + GN_EPS);
  }
}

// ---------------- build per-cell voxel slots (<=8 parents per 2x cell) ------
__global__ void slots_k(const int* __restrict__ seg, int* __restrict__ cnt,
                        int* __restrict__ slots, int N) {
  int i = blockIdx.x * 256 + threadIdx.x;
  if (i >= N) return;
  int s = seg[i];
  int p = atomicAdd(&cnt[s], 1);
  if (p < 8) slots[s * 8 + p] = i;
}

// ---------------- downsample: x_d = mean(f), h_d = mean(silu(gn1(f))) -------
__global__ void down_k(const void* __restrict__ feats, const int* __restrict__ slots,
                       const int* __restrict__ cnt, const float* __restrict__ fin1,
                       const void* __restrict__ gw, const void* __restrict__ gb,
                       bf16* __restrict__ xd, bf16* __restrict__ hd, int M,
                       const int* __restrict__ flagp) {
  const int f = *flagp;
  int cell = blockIdx.x * 2 + (threadIdx.x >> 7);
  int c = threadIdx.x & 127;
  if (cell >= M) return;
  int n = min(cnt[cell], 8);
  int g = c >> 2;
  float mu = fin1[g], is = fin1[32 + g];
  float w = ldf(gw, c, f), b = ldf(gb, c, f);
  float xs = 0.f, hs = 0.f;
  for (int j = 0; j < n; ++j) {
    int v = slots[cell * 8 + j];
    float fv = ldf(feats, (size_t)v * 128 + c, f);
    xs += fv;
    hs += silu_f((fv - mu) * is * w + b);
  }
  float inv = 1.f / (float)max(n, 1);
  xd[(size_t)cell * 128 + c] = __float2bfloat16(xs * inv);
  hd[(size_t)cell * 128 + c] = __float2bfloat16(hs * inv);
}

// ---------------- h2 = silu(gn2(h1)) in-place (h1 is always bf16) -----------
__global__ void act2_k(bf16* __restrict__ h, const float* __restrict__ fin2,
                       const void* __restrict__ gw, const void* __restrict__ gb,
                       size_t total, const int* __restrict__ flagp) {
  const int f = *flagp;
  size_t i = (size_t)blockIdx.x * 256 + threadIdx.x;
  if (i >= total) return;
  int c = (int)(i & 255);
  int g = c >> 3;
  float v = __bfloat162float(h[i]);
  float t = (v - fin2[g]) * fin2[32 + g] * ldf(gw, c, f) + ldf(gb, c, f);
  h[i] = __float2bfloat16(silu_f(t));
}

// ---------------- gather-GEMM conv: out[i] = sum_k Wt[k]^T A[nbr[i,k]] + b --
// Wt layout: [k][cout][cin] (k-major contiguous cin). If SKIP: 28th block at
// Wt + 27*256*CIN with layout [cout][128] fed by Xd (src = self).
// Staging: plain per-lane uint4 loads + LDS scatter stores (divergence-safe).
template <int CIN, bool SKIP>
__global__ __launch_bounds__(256, 2) void conv_k(
    const bf16* __restrict__ A, const bf16* __restrict__ Wt,
    const void* __restrict__ bias, const void* __restrict__ bias2,
    const bf16* __restrict__ Xd, const int* __restrict__ nbr,
    void* __restrict__ out, int M,
    const int* __restrict__ biasflagp, const int* __restrict__ outflagp) {
  __shared__ alignas(16) char lA[128 * 64];
  __shared__ alignas(16) char lB[128 * 64];
  const int bflag = *biasflagp, oflag = *outflagp;
  const int tid = threadIdx.x;
  const int wave = tid >> 6, lane = tid & 63;
  const int row0 = blockIdx.y * 128, n0 = blockIdx.x * 128;
  const int wr = wave >> 1, wc = wave & 1;
  const int sr = wave * 16 + (lane >> 2);  // staging row/col in [0,64)
  const int ch4 = lane & 3;                // 16B chunk within 64B row
  const int mrow = lane & 15, quad = lane >> 4;
  const int c1 = n0 + sr;

  f32x4 acc[4][4] = {};

  const int NK = SKIP ? 28 : 27;
  for (int kk = 0; kk < NK; ++kk) {
    const bool isW = (kk < 27);
    const int cink = isW ? CIN : 128;
    const bf16* Ab = isW ? A : Xd;
    const bf16* Wb = Wt + (size_t)(isW ? kk : 27) * (256 * CIN);
    int g1 = row0 + sr, g2 = g1 + 64;
    int src1 = -1, src2 = -1;
    if (isW) {
      if (g1 < M) src1 = nbr[(size_t)g1 * 27 + kk];
      if (g2 < M) src2 = nbr[(size_t)g2 * 27 + kk];
    } else {
      src1 = (g1 < M) ? g1 : -1;
      src2 = (g2 < M) ? g2 : -1;
    }
    const int ncb = cink >> 5;
    for (int cb = 0; cb < ncb; ++cb) {
      uint4 va1 = {0, 0, 0, 0}, va2 = {0, 0, 0, 0};
      if (src1 >= 0)
        va1 = *reinterpret_cast<const uint4*>(Ab + (size_t)src1 * cink + cb * 32 + ch4 * 8);
      if (src2 >= 0)
        va2 = *reinterpret_cast<const uint4*>(Ab + (size_t)src2 * cink + cb * 32 + ch4 * 8);
      uint4 vb1 = *reinterpret_cast<const uint4*>(Wb + (size_t)c1 * cink + cb * 32 + ch4 * 8);
      uint4 vb2 = *reinterpret_cast<const uint4*>(Wb + (size_t)(c1 + 64) * cink + cb * 32 + ch4 * 8);
      *reinterpret_cast<uint4*>(lA + (size_t)sr * 64 + ch4 * 16) = va1;
      *reinterpret_cast<uint4*>(lA + (size_t)(sr + 64) * 64 + ch4 * 16) = va2;
      *reinterpret_cast<uint4*>(lB + (size_t)sr * 64 + ch4 * 16) = vb1;
      *reinterpret_cast<uint4*>(lB + (size_t)(sr + 64) * 64 + ch4 * 16) = vb2;
      __syncthreads();
      // ---- MFMA 4x4 tiles of 16x16 per wave ----
      bf16x8 af[4], bfr[4];
#pragma unroll
      for (int i = 0; i < 4; ++i)
        af[i] = *reinterpret_cast<const bf16x8*>(
            lA + (size_t)(wr * 64 + i * 16 + mrow) * 64 + quad * 16);
#pragma unroll
      for (int j = 0; j < 4; ++j)
        bfr[j] = *reinterpret_cast<const bf16x8*>(
            lB + (size_t)(wc * 64 + j * 16 + mrow) * 64 + quad * 16);
#pragma unroll
      for (int i = 0; i < 4; ++i)
#pragma unroll
        for (int j = 0; j < 4; ++j)
          acc[i][j] = __builtin_amdgcn_mfma_f32_16x16x32_bf16(af[i], bfr[j],
                                                              acc[i][j], 0, 0, 0);
      __syncthreads();
    }
  }
  // ---- epilogue: bias (+bias2), store. C/D: col=lane&15, row=quad*4+r ------
#pragma unroll
  for (int j = 0; j < 4; ++j) {
    int col = n0 + wc * 64 + j * 16 + mrow;
    float bv = ldf(bias, col, bflag);
    if (SKIP) bv += ldf(bias2, col, bflag);
#pragma unroll
    for (int i = 0; i < 4; ++i) {
      int rb = row0 + wr * 64 + i * 16 + quad * 4;
#pragma unroll
      for (int r = 0; r < 4; ++r) {
        int row = rb + r;
        if (row < M) {
          size_t idx = (size_t)row * 256 + col;
          float val = acc[i][j][r] + bv;
          if (oflag) ((float*)out)[idx] = val;
          else ((bf16*)out)[idx] = __float2bfloat16(val);
        }
      }
    }
  }
}

extern "C" void kernel_launch(void* const* d_in, const int* in_sizes, int n_in,
                              void* d_out, int out_size, void* d_ws, size_t ws_size,
                              hipStream_t stream) {
  const void* feats = d_in[0];
  const void* gn1w = d_in[1];
  const void* gn1b = d_in[2];
  const void* W1 = d_in[3];
  const void* b1 = d_in[4];
  const void* gn2w = d_in[5];
  const void* gn2b = d_in[6];
  const void* W2 = d_in[7];
  const void* b2 = d_in[8];
  const void* Wsk = d_in[9];
  const void* bsk = d_in[10];
  const int* pool = (const int*)d_in[11];
  const int* nbr = (const int*)d_in[12];
  const int N = in_sizes[0] / 128;
  const int M = out_size / 256;

  char* ws = (char*)d_ws;
  auto aup = [](size_t x) { return (x + 255) & ~(size_t)255; };
  float* raw1 = (float*)(ws + 0);      // 64 f32
  float* raw2 = (float*)(ws + 256);    // 64 f32
  int* flag = (int*)(ws + 512);        // dtype flag (1 = f32 inputs)
  int* zeroflag = (int*)(ws + 516);    // always 0 (force-bf16 flag)
  int* cnt = (int*)(ws + 1024);        // M i32
  size_t o = aup(1024 + (size_t)M * 4);
  float* fin1 = (float*)(ws + o); o += 256;
  float* fin2 = (float*)(ws + o); o += 256;
  int* slots = (int*)(ws + o); o = aup(o + (size_t)M * 32);
  bf16* xd = (bf16*)(ws + o); o += (size_t)M * 256;
  bf16* hd = (bf16*)(ws + o); o += (size_t)M * 256;
  bf16* h1 = (bf16*)(ws + o); o += (size_t)M * 512;
  bf16* wt1 = (bf16*)(ws + o); o += (size_t)27 * 256 * 128 * 2;
  bf16* wt2 = (bf16*)(ws + o); o += ((size_t)27 * 256 * 256 + 256 * 128) * 2;
  (void)ws_size; (void)n_in;

  // zero stats + flags + counts (ws is poisoned 0xAA before every call)
  hipMemsetAsync(ws, 0, 1024 + (size_t)M * 4, stream);

  // dtype detection (writes flag)
  detect_k<<<1, 64, 0, stream>>>(gn1w, flag);

  // weight transposes: W[k][ci][co] -> Wt[k][co][ci]; Wskip appended to wt2
  transpose_k<<<dim3(4 * 8, 27), 256, 0, stream>>>(W1, wt1, 128, 256, flag);
  transpose_k<<<dim3(8 * 8, 27), 256, 0, stream>>>(W2, wt2, 256, 256, flag);
  transpose_k<<<dim3(4 * 8, 1), 256, 0, stream>>>(
      Wsk, wt2 + (size_t)27 * 256 * 256, 128, 256, flag);

  // GN1 stats over all N voxels
  gn_stats_k<<<512, 256, 0, stream>>>(feats, raw1, N, 128, flag);
  gn_fin_k<<<1, 64, 0, stream>>>(raw1, fin1, (float)N * 4.f);

  // downsample structure + gather
  slots_k<<<(N + 255) / 256, 256, 0, stream>>>(pool, cnt, slots, N);
  down_k<<<(M + 1) / 2, 256, 0, stream>>>(feats, slots, cnt, fin1, gn1w, gn1b,
                                          xd, hd, M, flag);

  // conv1: h1 = gatherGEMM(hd, W1) + b1   (h1 is bf16 -> outflag = zeroflag)
  conv_k<128, false><<<dim3(2, (M + 127) / 128), 256, 0, stream>>>(
      hd, wt1, b1, nullptr, nullptr, nbr, h1, M, flag, zeroflag);

  // GN2 + SiLU (in place on h1; h1 is bf16 -> force-bf16 flag for stats)
  gn_stats_k<<<512, 256, 0, stream>>>(h1, raw2, M, 256, zeroflag);
  gn_fin_k<<<1, 64, 0, stream>>>(raw2, fin2, (float)M * 8.f);
  act2_k<<<(int)(((size_t)M * 256 + 255) / 256), 256, 0, stream>>>(
      h1, fin2, gn2w, gn2b, (size_t)M * 256, flag);

  // conv2 + fused skip (28th "neighbor" = self over xd with Wskip^T) + b2+bskip
  conv_k<256, true><<<dim3(2, (M + 127) / 128), 256, 0, stream>>>(
      h1, wt2, b2, bsk, xd, nbr, d_out, M, flag, flag);
}